// Round 1
// baseline (529.788 us; speedup 1.0000x reference)
//
#include <hip/hip_runtime.h>
#include <math.h>

#define BM 64
#define BN 64
#define BK 32

// C[M,N] = A[M,K] @ W^T + bias, where W rows 0..n0-1 come from W0/b0 and the
// rest from W1/b1 (lets one kernel produce the concatenated [Wo;Wa] output).
// Requires M%64==0, N%64==0, K%32==0, all row-major, 16B-aligned rows.
__global__ __launch_bounds__(256) void msda_gemm_bt_bias(
    const float* __restrict__ A,
    const float* __restrict__ W0, const float* __restrict__ b0, int n0,
    const float* __restrict__ W1, const float* __restrict__ b1,
    float* __restrict__ C, int M, int N, int K)
{
    __shared__ float As[BK][BM];   // transposed tiles: As[k][m]
    __shared__ float Bs[BK][BN];   // Bs[k][n]
    const int bm = blockIdx.x * BM;
    const int bn = blockIdx.y * BN;
    const int tid = threadIdx.x;
    const int tm = (tid >> 4) << 2;   // 0..60
    const int tn = (tid & 15) << 2;   // 0..60

    float acc[4][4] = {{0.f, 0.f, 0.f, 0.f}, {0.f, 0.f, 0.f, 0.f},
                       {0.f, 0.f, 0.f, 0.f}, {0.f, 0.f, 0.f, 0.f}};

    for (int k0 = 0; k0 < K; k0 += BK) {
        // stage 64x32 A-tile and 64x32 W-tile (2048 floats each; 8/thread)
        #pragma unroll
        for (int it = 0; it < 2; ++it) {
            int idx = tid + it * 256;       // 0..511
            int r   = idx >> 3;             // 0..63
            int c4  = (idx & 7) << 2;       // 0,4,...,28
            float4 va = *(const float4*)(A + (size_t)(bm + r) * K + k0 + c4);
            As[c4 + 0][r] = va.x; As[c4 + 1][r] = va.y;
            As[c4 + 2][r] = va.z; As[c4 + 3][r] = va.w;
            int n = bn + r;
            const float* Wr = (n < n0) ? (W0 + (size_t)n * K)
                                       : (W1 + (size_t)(n - n0) * K);
            float4 vb = *(const float4*)(Wr + k0 + c4);
            Bs[c4 + 0][r] = vb.x; Bs[c4 + 1][r] = vb.y;
            Bs[c4 + 2][r] = vb.z; Bs[c4 + 3][r] = vb.w;
        }
        __syncthreads();
        #pragma unroll
        for (int k = 0; k < BK; ++k) {
            float4 a = *(const float4*)(&As[k][tm]);
            float4 b = *(const float4*)(&Bs[k][tn]);
            acc[0][0] += a.x * b.x; acc[0][1] += a.x * b.y;
            acc[0][2] += a.x * b.z; acc[0][3] += a.x * b.w;
            acc[1][0] += a.y * b.x; acc[1][1] += a.y * b.y;
            acc[1][2] += a.y * b.z; acc[1][3] += a.y * b.w;
            acc[2][0] += a.z * b.x; acc[2][1] += a.z * b.y;
            acc[2][2] += a.z * b.z; acc[2][3] += a.z * b.w;
            acc[3][0] += a.w * b.x; acc[3][1] += a.w * b.y;
            acc[3][2] += a.w * b.z; acc[3][3] += a.w * b.w;
        }
        __syncthreads();
    }

    // epilogue: add bias, store as float4 per row
    float bias[4];
    #pragma unroll
    for (int j = 0; j < 4; ++j) {
        int n = bn + tn + j;
        bias[j] = (n < n0) ? b0[n] : b1[n - n0];
    }
    #pragma unroll
    for (int i = 0; i < 4; ++i) {
        float4 o;
        o.x = acc[i][0] + bias[0];
        o.y = acc[i][1] + bias[1];
        o.z = acc[i][2] + bias[2];
        o.w = acc[i][3] + bias[3];
        *(float4*)(C + (size_t)(bm + tm + i) * N + bn + tn) = o;
    }
}

// Per-query fused: softmax over P, sample-position math, trilinear gather,
// weighted sum into attn_feats. One block (256 threads) per query.
// Threads 0..31 (one per (h,p)) compute 8 corner (idx, weight) pairs with the
// attention weight folded in; then all 256 threads (h,d) gather-accumulate.
__global__ __launch_bounds__(256) void msda_sample_kernel(
    const float* __restrict__ C1,      // [BQ,128]: 96 offs + 32 attn logits
    const float* __restrict__ priors,  // [BQ,2]
    const float* __restrict__ val,     // [B,Ns,256]
    const int*   __restrict__ map_hw,  // [4][2] (H,W)
    const int*   __restrict__ map_offs,// [4]
    const int*   __restrict__ map_ids, // [B,Ns]
    float* __restrict__ out,           // [BQ,256]
    int Nq, int Ns)
{
    const int bq = blockIdx.x;
    const int b  = bq / Nq;
    const int q  = bq - b * Nq;
    const int tid = threadIdx.x;

    __shared__ float s_w[32][8];
    __shared__ int   s_i[32][8];

    if (tid < 32) {
        const int h = tid >> 2;
        const int p = tid & 3;
        const float* sc = C1 + (size_t)bq * 128;
        float o0 = sc[h * 12 + p * 3 + 0];
        float o1 = sc[h * 12 + p * 3 + 1];
        float o2 = sc[h * 12 + p * 3 + 2];
        float logit = sc[96 + h * 4 + p];

        // softmax over the 4 points of this head (lanes 4h..4h+3)
        float m = logit;
        m = fmaxf(m, __shfl_xor(m, 1));
        m = fmaxf(m, __shfl_xor(m, 2));
        float e = expf(logit - m);
        float s = e;
        s += __shfl_xor(s, 1);
        s += __shfl_xor(s, 2);
        float attnw = e / s;

        int lid = map_ids[(size_t)b * Ns + q];
        float px = priors[(size_t)bq * 2 + 0];
        float py = priors[(size_t)bq * 2 + 1];
        int Hq = map_hw[lid * 2 + 0];
        int Wq = map_hw[lid * 2 + 1];
        float x = px + o0 / (float)Wq;
        float y = py + o1 / (float)Hq;

        float lvl_f = (float)lid + tanhf(o2);
        float l0f = floorf(lvl_f);
        int   l0  = (int)l0f;
        float wz  = lvl_f - l0f;

        #pragma unroll
        for (int sl = 0; sl < 2; ++sl) {
            int   lv = l0 + sl;
            float wl = sl ? wz : (1.0f - wz);
            float w4[4];
            int   i4[4];
            if (lv >= 0 && lv < 4) {
                int Hs  = map_hw[lv * 2 + 0];
                int Ws  = map_hw[lv * 2 + 1];
                int off = map_offs[lv];
                float xf = x * (float)Ws - 0.5f;
                float yf = y * (float)Hs - 0.5f;
                float x0f = floorf(xf), y0f = floorf(yf);
                int   x0  = (int)x0f,  y0  = (int)y0f;
                float dx = xf - x0f, dy = yf - y0f;
                #pragma unroll
                for (int j = 0; j < 4; ++j) {
                    int xi = x0 + (j & 1);
                    int yi = y0 + (j >> 1);
                    float w = ((j & 1) ? dx : 1.0f - dx) *
                              ((j >> 1) ? dy : 1.0f - dy);
                    bool ok = (xi >= 0) && (xi < Ws) && (yi >= 0) && (yi < Hs);
                    w4[j] = ok ? (w * wl * attnw) : 0.0f;
                    i4[j] = ok ? (off + yi * Ws + xi) : 0;
                }
            } else {
                #pragma unroll
                for (int j = 0; j < 4; ++j) { w4[j] = 0.0f; i4[j] = 0; }
            }
            #pragma unroll
            for (int j = 0; j < 4; ++j) {
                s_w[tid][sl * 4 + j] = w4[j];
                s_i[tid][sl * 4 + j] = i4[j];
            }
        }
    }
    __syncthreads();

    const int h = tid >> 5;    // 0..7
    const int d = tid & 31;    // 0..31
    const float* vb = val + (size_t)b * Ns * 256 + h * 32 + d;
    float acc = 0.0f;
    const int hp0 = h * 4;
    #pragma unroll
    for (int p = 0; p < 4; ++p) {
        #pragma unroll
        for (int j = 0; j < 8; ++j) {
            float w = s_w[hp0 + p][j];
            if (w != 0.0f) {
                acc += w * vb[(size_t)s_i[hp0 + p][j] * 256];
            }
        }
    }
    out[(size_t)bq * 256 + tid] = acc;
}

extern "C" void kernel_launch(void* const* d_in, const int* in_sizes, int n_in,
                              void* d_out, int out_size, void* d_ws, size_t ws_size,
                              hipStream_t stream) {
    const float* in_feats      = (const float*)d_in[0];
    const float* sample_priors = (const float*)d_in[1];
    const float* sample_feats  = (const float*)d_in[2];
    const int*   map_hw        = (const int*)d_in[3];
    const int*   map_offs      = (const int*)d_in[4];
    const int*   map_ids       = (const int*)d_in[5];
    const float* Wo            = (const float*)d_in[6];
    const float* bo            = (const float*)d_in[7];
    const float* Wa            = (const float*)d_in[8];
    const float* ba            = (const float*)d_in[9];
    const float* Wv            = (const float*)d_in[10];
    const float* bv            = (const float*)d_in[11];
    const float* Wout          = (const float*)d_in[12];
    const float* bout          = (const float*)d_in[13];
    float* out = (float*)d_out;

    const int B = 2, Nq = 21760, Din = 256;
    const int Ns = in_sizes[2] / (B * Din);   // 21760
    const int BQ = B * Nq;                    // 43520

    // val lives in d_out (dead before final GEMM overwrites it).
    float* val = out;                                   // [B*Ns, 256]
    float* C1  = (float*)d_ws;                          // [BQ, 128]
    float* af  = (float*)d_ws + (size_t)BQ * 128;       // [BQ, 256]

    dim3 blk(256);

    // K1: val = sample_feats @ Wv^T + bv
    msda_gemm_bt_bias<<<dim3(BQ / BM, 256 / BN), blk, 0, stream>>>(
        sample_feats, Wv, bv, 1 << 30, Wv, bv, val, B * Ns, 256, Din);

    // K2: C1 = in_feats @ [Wo;Wa]^T + [bo;ba]
    msda_gemm_bt_bias<<<dim3(BQ / BM, 128 / BN), blk, 0, stream>>>(
        in_feats, Wo, bo, 96, Wa, ba, C1, BQ, 128, Din);

    // K3: fused softmax + trilinear sampling -> attn_feats
    msda_sample_kernel<<<dim3(BQ), blk, 0, stream>>>(
        C1, sample_priors, val, map_hw, map_offs, map_ids, af, Nq, Ns);

    // K4: out = attn_feats @ Wout^T + bout
    msda_gemm_bt_bias<<<dim3(BQ / BM, 256 / BN), blk, 0, stream>>>(
        af, Wout, bout, 1 << 30, Wout, bout, out, BQ, 256, Din);
}

// Round 2
// 353.369 us; speedup vs baseline: 1.4992x; 1.4992x over previous
//
#include <hip/hip_runtime.h>
#include <math.h>

#define BM 64
#define BN 64
#define BK 32

// C[M,N] = A[M,K] @ W^T + bias, where W rows 0..n0-1 come from W0/b0 and the
// rest from W1/b1 (lets one kernel produce the concatenated [Wo;Wa] output).
// Requires M%64==0, N%64==0, K%32==0, all row-major, 16B-aligned rows.
__global__ __launch_bounds__(256) void msda_gemm_bt_bias(
    const float* __restrict__ A,
    const float* __restrict__ W0, const float* __restrict__ b0, int n0,
    const float* __restrict__ W1, const float* __restrict__ b1,
    float* __restrict__ C, int M, int N, int K)
{
    __shared__ float As[BK][BM];   // transposed tiles: As[k][m]
    __shared__ float Bs[BK][BN];   // Bs[k][n]
    const int bm = blockIdx.x * BM;
    const int bn = blockIdx.y * BN;
    const int tid = threadIdx.x;
    const int tm = (tid >> 4) << 2;   // 0..60
    const int tn = (tid & 15) << 2;   // 0..60

    float acc[4][4] = {{0.f, 0.f, 0.f, 0.f}, {0.f, 0.f, 0.f, 0.f},
                       {0.f, 0.f, 0.f, 0.f}, {0.f, 0.f, 0.f, 0.f}};

    for (int k0 = 0; k0 < K; k0 += BK) {
        // stage 64x32 A-tile and 64x32 W-tile (2048 floats each; 8/thread)
        #pragma unroll
        for (int it = 0; it < 2; ++it) {
            int idx = tid + it * 256;       // 0..511
            int r   = idx >> 3;             // 0..63
            int c4  = (idx & 7) << 2;       // 0,4,...,28
            float4 va = *(const float4*)(A + (size_t)(bm + r) * K + k0 + c4);
            As[c4 + 0][r] = va.x; As[c4 + 1][r] = va.y;
            As[c4 + 2][r] = va.z; As[c4 + 3][r] = va.w;
            int n = bn + r;
            const float* Wr = (n < n0) ? (W0 + (size_t)n * K)
                                       : (W1 + (size_t)(n - n0) * K);
            float4 vb = *(const float4*)(Wr + k0 + c4);
            Bs[c4 + 0][r] = vb.x; Bs[c4 + 1][r] = vb.y;
            Bs[c4 + 2][r] = vb.z; Bs[c4 + 3][r] = vb.w;
        }
        __syncthreads();
        #pragma unroll
        for (int k = 0; k < BK; ++k) {
            float4 a = *(const float4*)(&As[k][tm]);
            float4 b = *(const float4*)(&Bs[k][tn]);
            acc[0][0] += a.x * b.x; acc[0][1] += a.x * b.y;
            acc[0][2] += a.x * b.z; acc[0][3] += a.x * b.w;
            acc[1][0] += a.y * b.x; acc[1][1] += a.y * b.y;
            acc[1][2] += a.y * b.z; acc[1][3] += a.y * b.w;
            acc[2][0] += a.z * b.x; acc[2][1] += a.z * b.y;
            acc[2][2] += a.z * b.z; acc[2][3] += a.z * b.w;
            acc[3][0] += a.w * b.x; acc[3][1] += a.w * b.y;
            acc[3][2] += a.w * b.z; acc[3][3] += a.w * b.w;
        }
        __syncthreads();
    }

    // epilogue: add bias, store as float4 per row
    float bias[4];
    #pragma unroll
    for (int j = 0; j < 4; ++j) {
        int n = bn + tn + j;
        bias[j] = (n < n0) ? b0[n] : b1[n - n0];
    }
    #pragma unroll
    for (int i = 0; i < 4; ++i) {
        float4 o;
        o.x = acc[i][0] + bias[0];
        o.y = acc[i][1] + bias[1];
        o.z = acc[i][2] + bias[2];
        o.w = acc[i][3] + bias[3];
        *(float4*)(C + (size_t)(bm + tm + i) * N + bn + tn) = o;
    }
}

// Per-query fused: softmax over P, sample-position math, trilinear gather,
// weighted sum into attn_feats. One block (256 threads) per query.
// Threads 0..31 (one per (h,p)) compute 8 corner (pre-scaled idx, weight)
// pairs with the attention weight folded in. Then thread (p,h,d4) gathers
// 8 unconditional float4 loads (invalid corners -> idx 0, weight 0: L1-hot,
// keeps all 8 loads in flight with one waitcnt) and p is reduced via LDS.
__global__ __launch_bounds__(256) void msda_sample_kernel(
    const float* __restrict__ C1,      // [BQ,128]: 96 offs + 32 attn logits
    const float* __restrict__ priors,  // [BQ,2]
    const float* __restrict__ val,     // [B,Ns,256]
    const int*   __restrict__ map_hw,  // [4][2] (H,W)
    const int*   __restrict__ map_offs,// [4]
    const int*   __restrict__ map_ids, // [B,Ns]
    float* __restrict__ out,           // [BQ,256]
    int Nq, int Ns)
{
    const int bq = blockIdx.x;
    const int b  = bq / Nq;
    const int q  = bq - b * Nq;
    const int tid = threadIdx.x;

    __shared__ float  s_w[32][9];   // +1 pad: kills 8-way bank conflict
    __shared__ int    s_i[32][9];   // pre-multiplied by 256 (row elements)
    __shared__ float4 s_red[256];

    if (tid < 32) {
        const int h = tid >> 2;
        const int p = tid & 3;
        const float* sc = C1 + (size_t)bq * 128;
        float o0 = sc[h * 12 + p * 3 + 0];
        float o1 = sc[h * 12 + p * 3 + 1];
        float o2 = sc[h * 12 + p * 3 + 2];
        float logit = sc[96 + h * 4 + p];

        // softmax over the 4 points of this head (lanes 4h..4h+3)
        float m = logit;
        m = fmaxf(m, __shfl_xor(m, 1));
        m = fmaxf(m, __shfl_xor(m, 2));
        float e = expf(logit - m);
        float s = e;
        s += __shfl_xor(s, 1);
        s += __shfl_xor(s, 2);
        float attnw = e / s;

        int lid = map_ids[(size_t)b * Ns + q];
        float px = priors[(size_t)bq * 2 + 0];
        float py = priors[(size_t)bq * 2 + 1];
        int Hq = map_hw[lid * 2 + 0];
        int Wq = map_hw[lid * 2 + 1];
        float x = px + o0 / (float)Wq;
        float y = py + o1 / (float)Hq;

        float lvl_f = (float)lid + tanhf(o2);
        float l0f = floorf(lvl_f);
        int   l0  = (int)l0f;
        float wz  = lvl_f - l0f;

        #pragma unroll
        for (int sl = 0; sl < 2; ++sl) {
            int   lv = l0 + sl;
            float wl = sl ? wz : (1.0f - wz);
            float w4[4];
            int   i4[4];
            if (lv >= 0 && lv < 4) {
                int Hs  = map_hw[lv * 2 + 0];
                int Ws  = map_hw[lv * 2 + 1];
                int off = map_offs[lv];
                float xf = x * (float)Ws - 0.5f;
                float yf = y * (float)Hs - 0.5f;
                float x0f = floorf(xf), y0f = floorf(yf);
                int   x0  = (int)x0f,  y0  = (int)y0f;
                float dx = xf - x0f, dy = yf - y0f;
                #pragma unroll
                for (int j = 0; j < 4; ++j) {
                    int xi = x0 + (j & 1);
                    int yi = y0 + (j >> 1);
                    float w = ((j & 1) ? dx : 1.0f - dx) *
                              ((j >> 1) ? dy : 1.0f - dy);
                    bool ok = (xi >= 0) && (xi < Ws) && (yi >= 0) && (yi < Hs);
                    w4[j] = ok ? (w * wl * attnw) : 0.0f;
                    i4[j] = ok ? ((off + yi * Ws + xi) << 8) : 0;
                }
            } else {
                #pragma unroll
                for (int j = 0; j < 4; ++j) { w4[j] = 0.0f; i4[j] = 0; }
            }
            #pragma unroll
            for (int j = 0; j < 4; ++j) {
                s_w[tid][sl * 4 + j] = w4[j];
                s_i[tid][sl * 4 + j] = i4[j];
            }
        }
    }
    __syncthreads();

    const int p  = tid >> 6;         // 0..3
    const int h  = (tid >> 3) & 7;   // 0..7
    const int d4 = tid & 7;          // 0..7
    const int hp = h * 4 + p;

    float w[8];
    int   ix[8];
    #pragma unroll
    for (int j = 0; j < 8; ++j) { w[j] = s_w[hp][j]; ix[j] = s_i[hp][j]; }

    const float* vb = val + (size_t)b * Ns * 256 + h * 32 + d4 * 4;
    float4 acc = {0.f, 0.f, 0.f, 0.f};
    #pragma unroll
    for (int j = 0; j < 8; ++j) {
        float4 v = *(const float4*)(vb + (size_t)ix[j]);
        acc.x += w[j] * v.x;
        acc.y += w[j] * v.y;
        acc.z += w[j] * v.z;
        acc.w += w[j] * v.w;
    }
    s_red[tid] = acc;
    __syncthreads();

    if (tid < 64) {
        float4 a0 = s_red[tid];
        float4 a1 = s_red[tid + 64];
        float4 a2 = s_red[tid + 128];
        float4 a3 = s_red[tid + 192];
        float4 o;
        o.x = a0.x + a1.x + a2.x + a3.x;
        o.y = a0.y + a1.y + a2.y + a3.y;
        o.z = a0.z + a1.z + a2.z + a3.z;
        o.w = a0.w + a1.w + a2.w + a3.w;
        *(float4*)(out + (size_t)bq * 256 + tid * 4) = o;
    }
}

extern "C" void kernel_launch(void* const* d_in, const int* in_sizes, int n_in,
                              void* d_out, int out_size, void* d_ws, size_t ws_size,
                              hipStream_t stream) {
    const float* in_feats      = (const float*)d_in[0];
    const float* sample_priors = (const float*)d_in[1];
    const float* sample_feats  = (const float*)d_in[2];
    const int*   map_hw        = (const int*)d_in[3];
    const int*   map_offs      = (const int*)d_in[4];
    const int*   map_ids       = (const int*)d_in[5];
    const float* Wo            = (const float*)d_in[6];
    const float* bo            = (const float*)d_in[7];
    const float* Wa            = (const float*)d_in[8];
    const float* ba            = (const float*)d_in[9];
    const float* Wv            = (const float*)d_in[10];
    const float* bv            = (const float*)d_in[11];
    const float* Wout          = (const float*)d_in[12];
    const float* bout          = (const float*)d_in[13];
    float* out = (float*)d_out;

    const int B = 2, Nq = 21760, Din = 256;
    const int Ns = in_sizes[2] / (B * Din);   // 21760
    const int BQ = B * Nq;                    // 43520

    // val lives in d_out (dead before final GEMM overwrites it).
    float* val = out;                                   // [B*Ns, 256]
    float* C1  = (float*)d_ws;                          // [BQ, 128]
    float* af  = (float*)d_ws + (size_t)BQ * 128;       // [BQ, 256]

    dim3 blk(256);

    // K1: val = sample_feats @ Wv^T + bv
    msda_gemm_bt_bias<<<dim3(BQ / BM, 256 / BN), blk, 0, stream>>>(
        sample_feats, Wv, bv, 1 << 30, Wv, bv, val, B * Ns, 256, Din);

    // K2: C1 = in_feats @ [Wo;Wa]^T + [bo;ba]
    msda_gemm_bt_bias<<<dim3(BQ / BM, 128 / BN), blk, 0, stream>>>(
        in_feats, Wo, bo, 96, Wa, ba, C1, BQ, 128, Din);

    // K3: fused softmax + trilinear sampling -> attn_feats
    msda_sample_kernel<<<dim3(BQ), blk, 0, stream>>>(
        C1, sample_priors, val, map_hw, map_offs, map_ids, af, Nq, Ns);

    // K4: out = attn_feats @ Wout^T + bout
    msda_gemm_bt_bias<<<dim3(BQ / BM, 256 / BN), blk, 0, stream>>>(
        af, Wout, bout, 1 << 30, Wout, bout, out, BQ, 256, Din);
}

// Round 3
// 169.888 us; speedup vs baseline: 3.1185x; 2.0800x over previous
//
#include <hip/hip_runtime.h>
#include <hip/hip_bf16.h>
#include <math.h>

typedef __bf16 bf16x8 __attribute__((ext_vector_type(8)));
typedef float f32x4 __attribute__((ext_vector_type(4)));
typedef unsigned short ushort8 __attribute__((ext_vector_type(8)));

static __device__ __forceinline__ unsigned short f2bf(float f) {
    union { float f; unsigned u; } c; c.f = f;
    unsigned r = c.u + 0x7FFFu + ((c.u >> 16) & 1u);   // RNE
    return (unsigned short)(r >> 16);
}

// ---------------------------------------------------------------------------
// Weight pre-conversion: fp32 -> bf16, concatenating [Wo;Wa] and [bo;ba].
__global__ __launch_bounds__(256) void convert_weights(
    const float* __restrict__ Wv, const float* __restrict__ Wo,
    const float* __restrict__ Wa, const float* __restrict__ Wout,
    const float* __restrict__ bo, const float* __restrict__ ba,
    unsigned short* __restrict__ Wv_b, unsigned short* __restrict__ Woa_b,
    unsigned short* __restrict__ Wout_b, float* __restrict__ boa)
{
    int gid = blockIdx.x * blockDim.x + threadIdx.x;
    int stride = gridDim.x * blockDim.x;
    for (int i = gid; i < 163840; i += stride) {
        if (i < 65536)       Wv_b[i] = f2bf(Wv[i]);
        else if (i < 90112)  Woa_b[i - 65536] = f2bf(Wo[i - 65536]);
        else if (i < 98304)  Woa_b[i - 65536] = f2bf(Wa[i - 90112]);
        else                 Wout_b[i - 98304] = f2bf(Wout[i - 98304]);
    }
    if (gid < 96)       boa[gid] = bo[gid];
    else if (gid < 128) boa[gid] = ba[gid - 96];
}

// ---------------------------------------------------------------------------
// C[M,N] = A[M,K] @ W^T + bias  via mfma_f32_16x16x32_bf16.
// W is bf16 [N][K] row-major. A is fp32 (converted in staging) or bf16.
// BM=64 fixed; BN = WN*64; block = WN waves, each wave computes 64x64.
// LDS rows padded to 72 shorts (144B): fragment ds_read_b128 is ~2-way = free.
template<int WN, bool A_BF16>
__global__ __launch_bounds__(WN * 64) void gemm_mfma(
    const void* __restrict__ Av, const unsigned short* __restrict__ W,
    const float* __restrict__ bias, float* __restrict__ C,
    int M, int N, int K)
{
    constexpr int BM = 64;
    constexpr int BN = WN * 64;
    constexpr int BK = 64;
    constexpr int NTHR = WN * 64;
    constexpr int LDP = 72;                 // padded row stride (shorts)

    __shared__ __align__(16) unsigned short smem[(BM + BN) * LDP];
    unsigned short* As = smem;              // [BM][LDP]
    unsigned short* Bs = smem + BM * LDP;   // [BN][LDP]

    const int bm  = blockIdx.x * BM;
    const int bn  = blockIdx.y * BN;
    const int tid = threadIdx.x;
    const int wid = tid >> 6;
    const int lane = tid & 63;
    const int lr = lane & 15;               // col-in-fragment
    const int lg = lane >> 4;               // 0..3

    f32x4 acc[4][4];
    #pragma unroll
    for (int mi = 0; mi < 4; ++mi)
        #pragma unroll
        for (int ni = 0; ni < 4; ++ni)
            acc[mi][ni] = (f32x4){0.f, 0.f, 0.f, 0.f};

    for (int kt = 0; kt < K; kt += BK) {
        // ---- stage A tile (BM x 64k) -> bf16 LDS
        if (A_BF16) {
            const unsigned short* A = (const unsigned short*)Av;
            #pragma unroll
            for (int u = tid; u < BM * 8; u += NTHR) {
                int r = u >> 3, kb = u & 7;
                ushort8 v = *(const ushort8*)(A + (size_t)(bm + r) * K + kt + kb * 8);
                *(ushort8*)(As + r * LDP + kb * 8) = v;
            }
        } else {
            const float* A = (const float*)Av;
            #pragma unroll
            for (int u = tid; u < BM * 8; u += NTHR) {
                int r = u >> 3, kb = u & 7;
                const float* src = A + (size_t)(bm + r) * K + kt + kb * 8;
                float4 f0 = *(const float4*)(src);
                float4 f1 = *(const float4*)(src + 4);
                ushort8 v;
                v[0] = f2bf(f0.x); v[1] = f2bf(f0.y);
                v[2] = f2bf(f0.z); v[3] = f2bf(f0.w);
                v[4] = f2bf(f1.x); v[5] = f2bf(f1.y);
                v[6] = f2bf(f1.z); v[7] = f2bf(f1.w);
                *(ushort8*)(As + r * LDP + kb * 8) = v;
            }
        }
        // ---- stage B tile (BN x 64k), already bf16
        #pragma unroll
        for (int u = tid; u < BN * 8; u += NTHR) {
            int r = u >> 3, kb = u & 7;
            ushort8 v = *(const ushort8*)(W + (size_t)(bn + r) * K + kt + kb * 8);
            *(ushort8*)(Bs + r * LDP + kb * 8) = v;
        }
        __syncthreads();

        #pragma unroll
        for (int kk = 0; kk < 2; ++kk) {
            bf16x8 fa[4], fb[4];
            #pragma unroll
            for (int mi = 0; mi < 4; ++mi)
                fa[mi] = *(const bf16x8*)(As + (mi * 16 + lr) * LDP + kk * 32 + lg * 8);
            #pragma unroll
            for (int ni = 0; ni < 4; ++ni)
                fb[ni] = *(const bf16x8*)(Bs + (wid * 64 + ni * 16 + lr) * LDP + kk * 32 + lg * 8);
            #pragma unroll
            for (int mi = 0; mi < 4; ++mi)
                #pragma unroll
                for (int ni = 0; ni < 4; ++ni)
                    acc[mi][ni] = __builtin_amdgcn_mfma_f32_16x16x32_bf16(
                        fa[mi], fb[ni], acc[mi][ni], 0, 0, 0);
        }
        __syncthreads();
    }

    // epilogue: C/D layout col = lane&15, row = (lane>>4)*4 + reg  [m89]
    #pragma unroll
    for (int ni = 0; ni < 4; ++ni) {
        int col = bn + wid * 64 + ni * 16 + lr;
        float bv = bias[col];
        #pragma unroll
        for (int mi = 0; mi < 4; ++mi) {
            #pragma unroll
            for (int r = 0; r < 4; ++r) {
                int row = bm + mi * 16 + lg * 4 + r;
                C[(size_t)row * N + col] = acc[mi][ni][r] + bv;
            }
        }
    }
}

// ---------------------------------------------------------------------------
// Per-query fused: softmax over P, sample-position math, trilinear gather,
// weighted sum into attn_feats (bf16 out). One block (256 threads) per query.
__global__ __launch_bounds__(256) void msda_sample_kernel(
    const float* __restrict__ C1,      // [BQ,128]: 96 offs + 32 attn logits
    const float* __restrict__ priors,  // [BQ,2]
    const float* __restrict__ val,     // [B,Ns,256] fp32
    const int*   __restrict__ map_hw,  // [4][2] (H,W)
    const int*   __restrict__ map_offs,// [4]
    const int*   __restrict__ map_ids, // [B,Ns]
    unsigned short* __restrict__ out,  // [BQ,256] bf16
    int Nq, int Ns)
{
    const int bq = blockIdx.x;
    const int b  = bq / Nq;
    const int q  = bq - b * Nq;
    const int tid = threadIdx.x;

    __shared__ float  s_w[32][9];   // +1 pad: kills 8-way bank conflict
    __shared__ int    s_i[32][9];   // pre-multiplied by 256 (row elements)
    __shared__ float4 s_red[256];

    if (tid < 32) {
        const int h = tid >> 2;
        const int p = tid & 3;
        const float* sc = C1 + (size_t)bq * 128;
        float o0 = sc[h * 12 + p * 3 + 0];
        float o1 = sc[h * 12 + p * 3 + 1];
        float o2 = sc[h * 12 + p * 3 + 2];
        float logit = sc[96 + h * 4 + p];

        float m = logit;
        m = fmaxf(m, __shfl_xor(m, 1));
        m = fmaxf(m, __shfl_xor(m, 2));
        float e = expf(logit - m);
        float s = e;
        s += __shfl_xor(s, 1);
        s += __shfl_xor(s, 2);
        float attnw = e / s;

        int lid = map_ids[(size_t)b * Ns + q];
        float px = priors[(size_t)bq * 2 + 0];
        float py = priors[(size_t)bq * 2 + 1];
        int Hq = map_hw[lid * 2 + 0];
        int Wq = map_hw[lid * 2 + 1];
        float x = px + o0 / (float)Wq;
        float y = py + o1 / (float)Hq;

        float lvl_f = (float)lid + tanhf(o2);
        float l0f = floorf(lvl_f);
        int   l0  = (int)l0f;
        float wz  = lvl_f - l0f;

        #pragma unroll
        for (int sl = 0; sl < 2; ++sl) {
            int   lv = l0 + sl;
            float wl = sl ? wz : (1.0f - wz);
            float w4[4];
            int   i4[4];
            if (lv >= 0 && lv < 4) {
                int Hs  = map_hw[lv * 2 + 0];
                int Ws  = map_hw[lv * 2 + 1];
                int off = map_offs[lv];
                float xf = x * (float)Ws - 0.5f;
                float yf = y * (float)Hs - 0.5f;
                float x0f = floorf(xf), y0f = floorf(yf);
                int   x0  = (int)x0f,  y0  = (int)y0f;
                float dx = xf - x0f, dy = yf - y0f;
                #pragma unroll
                for (int j = 0; j < 4; ++j) {
                    int xi = x0 + (j & 1);
                    int yi = y0 + (j >> 1);
                    float w = ((j & 1) ? dx : 1.0f - dx) *
                              ((j >> 1) ? dy : 1.0f - dy);
                    bool ok = (xi >= 0) && (xi < Ws) && (yi >= 0) && (yi < Hs);
                    w4[j] = ok ? (w * wl * attnw) : 0.0f;
                    i4[j] = ok ? ((off + yi * Ws + xi) << 8) : 0;
                }
            } else {
                #pragma unroll
                for (int j = 0; j < 4; ++j) { w4[j] = 0.0f; i4[j] = 0; }
            }
            #pragma unroll
            for (int j = 0; j < 4; ++j) {
                s_w[tid][sl * 4 + j] = w4[j];
                s_i[tid][sl * 4 + j] = i4[j];
            }
        }
    }
    __syncthreads();

    const int p  = tid >> 6;         // 0..3
    const int h  = (tid >> 3) & 7;   // 0..7
    const int d4 = tid & 7;          // 0..7
    const int hp = h * 4 + p;

    float w[8];
    int   ix[8];
    #pragma unroll
    for (int j = 0; j < 8; ++j) { w[j] = s_w[hp][j]; ix[j] = s_i[hp][j]; }

    const float* vb = val + (size_t)b * Ns * 256 + h * 32 + d4 * 4;
    float4 acc = {0.f, 0.f, 0.f, 0.f};
    #pragma unroll
    for (int j = 0; j < 8; ++j) {
        float4 v = *(const float4*)(vb + (size_t)ix[j]);
        acc.x += w[j] * v.x;
        acc.y += w[j] * v.y;
        acc.z += w[j] * v.z;
        acc.w += w[j] * v.w;
    }
    s_red[tid] = acc;
    __syncthreads();

    if (tid < 64) {
        float4 a0 = s_red[tid];
        float4 a1 = s_red[tid + 64];
        float4 a2 = s_red[tid + 128];
        float4 a3 = s_red[tid + 192];
        ushort4 o;
        o.x = f2bf(a0.x + a1.x + a2.x + a3.x);
        o.y = f2bf(a0.y + a1.y + a2.y + a3.y);
        o.z = f2bf(a0.z + a1.z + a2.z + a3.z);
        o.w = f2bf(a0.w + a1.w + a2.w + a3.w);
        *(ushort4*)(out + (size_t)bq * 256 + tid * 4) = o;
    }
}

extern "C" void kernel_launch(void* const* d_in, const int* in_sizes, int n_in,
                              void* d_out, int out_size, void* d_ws, size_t ws_size,
                              hipStream_t stream) {
    const float* in_feats      = (const float*)d_in[0];
    const float* sample_priors = (const float*)d_in[1];
    const float* sample_feats  = (const float*)d_in[2];
    const int*   map_hw        = (const int*)d_in[3];
    const int*   map_offs      = (const int*)d_in[4];
    const int*   map_ids       = (const int*)d_in[5];
    const float* Wo            = (const float*)d_in[6];
    const float* bo            = (const float*)d_in[7];
    const float* Wa            = (const float*)d_in[8];
    const float* ba            = (const float*)d_in[9];
    const float* Wv            = (const float*)d_in[10];
    const float* bv            = (const float*)d_in[11];
    const float* Wout          = (const float*)d_in[12];
    const float* bout          = (const float*)d_in[13];
    float* out = (float*)d_out;

    const int B = 2, Nq = 21760, Din = 256;
    const int Ns = in_sizes[2] / (B * Din);   // 21760
    const int BQ = B * Nq;                    // 43520

    // Workspace layout
    float* val = out;                                         // [B*Ns,256] f32 (d_out, dead before K4)
    float* C1  = (float*)d_ws;                                // [BQ,128] f32
    unsigned short* af = (unsigned short*)((char*)d_ws + (size_t)BQ * 128 * 4);   // [BQ,256] bf16
    char* wbase = (char*)d_ws + (size_t)BQ * 128 * 4 + (size_t)BQ * 256 * 2;
    unsigned short* Wv_b   = (unsigned short*)wbase;          // 65536
    unsigned short* Woa_b  = Wv_b + 65536;                    // 32768 ([Wo;Wa])
    unsigned short* Wout_b = Woa_b + 32768;                   // 65536
    float* boa = (float*)(Wout_b + 65536);                    // 128 ([bo;ba])

    // K0: weight conversion (tiny)
    convert_weights<<<dim3(160), dim3(256), 0, stream>>>(
        Wv, Wo, Wa, Wout, bo, ba, Wv_b, Woa_b, Wout_b, boa);

    // K1: val = sample_feats @ Wv^T + bv   [43520,256]x[256,256]
    gemm_mfma<4, false><<<dim3(BQ / 64, 1), dim3(256), 0, stream>>>(
        sample_feats, Wv_b, bv, val, B * Ns, 256, Din);

    // K2: C1 = in_feats @ [Wo;Wa]^T + [bo;ba]   [43520,256]x[256,128]
    gemm_mfma<2, false><<<dim3(BQ / 64, 1), dim3(128), 0, stream>>>(
        in_feats, Woa_b, boa, C1, BQ, 128, Din);

    // K3: fused softmax + trilinear sampling -> attn_feats (bf16)
    msda_sample_kernel<<<dim3(BQ), dim3(256), 0, stream>>>(
        C1, sample_priors, val, map_hw, map_offs, map_ids, af, Nq, Ns);

    // K4: out = attn_feats @ Wout^T + bout   [43520,256]x[256,256]
    gemm_mfma<4, true><<<dim3(BQ / 64, 1), dim3(256), 0, stream>>>(
        af, Wout_b, bout, out, BQ, 256, Din);
}

// Round 4
// 137.679 us; speedup vs baseline: 3.8480x; 1.2339x over previous
//
#include <hip/hip_runtime.h>
#include <hip/hip_bf16.h>
#include <math.h>

typedef __bf16 bf16x8 __attribute__((ext_vector_type(8)));
typedef float f32x4 __attribute__((ext_vector_type(4)));
typedef unsigned short ushort8 __attribute__((ext_vector_type(8)));

static __device__ __forceinline__ unsigned short f2bf(float f) {
    union { float f; unsigned u; } c; c.f = f;
    unsigned r = c.u + 0x7FFFu + ((c.u >> 16) & 1u);   // RNE
    return (unsigned short)(r >> 16);
}
static __device__ __forceinline__ float bf2f(unsigned short u) {
    union { unsigned u; float f; } c; c.u = ((unsigned)u) << 16;
    return c.f;
}

// ---------------------------------------------------------------------------
// Weight pre-conversion: fp32 -> bf16, concatenating [Wo;Wa] and [bo;ba].
__global__ __launch_bounds__(256) void convert_weights(
    const float* __restrict__ Wv, const float* __restrict__ Wo,
    const float* __restrict__ Wa, const float* __restrict__ Wout,
    const float* __restrict__ bo, const float* __restrict__ ba,
    unsigned short* __restrict__ Wv_b, unsigned short* __restrict__ Woa_b,
    unsigned short* __restrict__ Wout_b, float* __restrict__ boa)
{
    int gid = blockIdx.x * blockDim.x + threadIdx.x;
    int stride = gridDim.x * blockDim.x;
    for (int i = gid; i < 163840; i += stride) {
        if (i < 65536)       Wv_b[i] = f2bf(Wv[i]);
        else if (i < 90112)  Woa_b[i - 65536] = f2bf(Wo[i - 65536]);
        else if (i < 98304)  Woa_b[i - 65536] = f2bf(Wa[i - 90112]);
        else                 Wout_b[i - 98304] = f2bf(Wout[i - 98304]);
    }
    if (gid < 96)       boa[gid] = bo[gid];
    else if (gid < 128) boa[gid] = ba[gid - 96];
}

// ---------------------------------------------------------------------------
// C[M,N] = A[M,K] @ W^T + bias  via mfma_f32_16x16x32_bf16.
// W is bf16 [N][K] row-major. A is fp32 (converted in staging) or bf16.
// BM=64 fixed; BN = WN*64; block = WN waves, each wave computes 64x64.
template<int WN, bool A_BF16, bool OUT_BF16>
__global__ __launch_bounds__(WN * 64) void gemm_mfma(
    const void* __restrict__ Av, const unsigned short* __restrict__ W,
    const float* __restrict__ bias, void* __restrict__ Cv,
    int M, int N, int K)
{
    constexpr int BM = 64;
    constexpr int BN = WN * 64;
    constexpr int BK = 64;
    constexpr int NTHR = WN * 64;
    constexpr int LDP = 72;                 // padded row stride (shorts)

    __shared__ __align__(16) unsigned short smem[(BM + BN) * LDP];
    unsigned short* As = smem;              // [BM][LDP]
    unsigned short* Bs = smem + BM * LDP;   // [BN][LDP]

    const int bm  = blockIdx.x * BM;
    const int bn  = blockIdx.y * BN;
    const int tid = threadIdx.x;
    const int wid = tid >> 6;
    const int lane = tid & 63;
    const int lr = lane & 15;               // col-in-fragment
    const int lg = lane >> 4;               // 0..3

    f32x4 acc[4][4];
    #pragma unroll
    for (int mi = 0; mi < 4; ++mi)
        #pragma unroll
        for (int ni = 0; ni < 4; ++ni)
            acc[mi][ni] = (f32x4){0.f, 0.f, 0.f, 0.f};

    for (int kt = 0; kt < K; kt += BK) {
        // ---- stage A tile (BM x 64k) -> bf16 LDS
        if (A_BF16) {
            const unsigned short* A = (const unsigned short*)Av;
            #pragma unroll
            for (int u = tid; u < BM * 8; u += NTHR) {
                int r = u >> 3, kb = u & 7;
                ushort8 v = *(const ushort8*)(A + (size_t)(bm + r) * K + kt + kb * 8);
                *(ushort8*)(As + r * LDP + kb * 8) = v;
            }
        } else {
            const float* A = (const float*)Av;
            #pragma unroll
            for (int u = tid; u < BM * 8; u += NTHR) {
                int r = u >> 3, kb = u & 7;
                const float* src = A + (size_t)(bm + r) * K + kt + kb * 8;
                float4 f0 = *(const float4*)(src);
                float4 f1 = *(const float4*)(src + 4);
                ushort8 v;
                v[0] = f2bf(f0.x); v[1] = f2bf(f0.y);
                v[2] = f2bf(f0.z); v[3] = f2bf(f0.w);
                v[4] = f2bf(f1.x); v[5] = f2bf(f1.y);
                v[6] = f2bf(f1.z); v[7] = f2bf(f1.w);
                *(ushort8*)(As + r * LDP + kb * 8) = v;
            }
        }
        // ---- stage B tile (BN x 64k), already bf16
        #pragma unroll
        for (int u = tid; u < BN * 8; u += NTHR) {
            int r = u >> 3, kb = u & 7;
            ushort8 v = *(const ushort8*)(W + (size_t)(bn + r) * K + kt + kb * 8);
            *(ushort8*)(Bs + r * LDP + kb * 8) = v;
        }
        __syncthreads();

        #pragma unroll
        for (int kk = 0; kk < 2; ++kk) {
            bf16x8 fa[4], fb[4];
            #pragma unroll
            for (int mi = 0; mi < 4; ++mi)
                fa[mi] = *(const bf16x8*)(As + (mi * 16 + lr) * LDP + kk * 32 + lg * 8);
            #pragma unroll
            for (int ni = 0; ni < 4; ++ni)
                fb[ni] = *(const bf16x8*)(Bs + (wid * 64 + ni * 16 + lr) * LDP + kk * 32 + lg * 8);
            #pragma unroll
            for (int mi = 0; mi < 4; ++mi)
                #pragma unroll
                for (int ni = 0; ni < 4; ++ni)
                    acc[mi][ni] = __builtin_amdgcn_mfma_f32_16x16x32_bf16(
                        fa[mi], fb[ni], acc[mi][ni], 0, 0, 0);
        }
        __syncthreads();
    }

    // epilogue: C/D layout col = lane&15, row = (lane>>4)*4 + reg  [m89]
    #pragma unroll
    for (int ni = 0; ni < 4; ++ni) {
        int col = bn + wid * 64 + ni * 16 + lr;
        float bv = bias[col];
        #pragma unroll
        for (int mi = 0; mi < 4; ++mi) {
            #pragma unroll
            for (int r = 0; r < 4; ++r) {
                int row = bm + mi * 16 + lg * 4 + r;
                if (OUT_BF16) {
                    ((unsigned short*)Cv)[(size_t)row * N + col] =
                        f2bf(acc[mi][ni][r] + bv);
                } else {
                    ((float*)Cv)[(size_t)row * N + col] = acc[mi][ni][r] + bv;
                }
            }
        }
    }
}

// ---------------------------------------------------------------------------
// Per-query fused: softmax over P, sample-position math, trilinear gather of
// bf16 val, weighted sum into attn_feats (bf16 out). 2 queries per block.
// Per query (128 threads): 32 threads compute 8 corner (idx,weight) pairs,
// then thread (p,h,d8) does 8 unconditional 16B bf16x8 loads + fp32 FMA;
// p is reduced via padded LDS. Grid is XCD-chunk swizzled for L2 locality.
__global__ __launch_bounds__(256) void msda_sample_kernel(
    const float* __restrict__ C1,        // [BQ,128]: 96 offs + 32 attn logits
    const float* __restrict__ priors,    // [BQ,2]
    const unsigned short* __restrict__ val, // [B,Ns,256] bf16
    const int*   __restrict__ map_hw,    // [4][2] (H,W)
    const int*   __restrict__ map_offs,  // [4]
    const int*   __restrict__ map_ids,   // [B,Ns]
    unsigned short* __restrict__ out,    // [BQ,256] bf16
    int Nq, int Ns)
{
    // XCD-chunked swizzle (nwg % 8 == 0): contiguous chunk per XCD
    const int swz = (blockIdx.x & 7) * (gridDim.x >> 3) + (blockIdx.x >> 3);
    const int qh  = threadIdx.x >> 7;        // which query of the pair
    const int bq  = swz * 2 + qh;
    const int t   = threadIdx.x & 127;
    const int b   = bq / Nq;
    const int q   = bq - b * Nq;

    __shared__ float s_w[2][32][9];
    __shared__ int   s_i[2][32][9];
    __shared__ float s_red[2][4][32][9];   // [q][p][s][c], padded

    if (t < 32) {
        const int h = t >> 2;
        const int p = t & 3;
        const float* sc = C1 + (size_t)bq * 128;
        float o0 = sc[h * 12 + p * 3 + 0];
        float o1 = sc[h * 12 + p * 3 + 1];
        float o2 = sc[h * 12 + p * 3 + 2];
        float logit = sc[96 + h * 4 + p];

        // softmax over the 4 points of this head (lanes 4h..4h+3 in-wave)
        float m = logit;
        m = fmaxf(m, __shfl_xor(m, 1));
        m = fmaxf(m, __shfl_xor(m, 2));
        float e = expf(logit - m);
        float s = e;
        s += __shfl_xor(s, 1);
        s += __shfl_xor(s, 2);
        float attnw = e / s;

        int lid = map_ids[(size_t)b * Ns + q];
        float px = priors[(size_t)bq * 2 + 0];
        float py = priors[(size_t)bq * 2 + 1];
        int Hq = map_hw[lid * 2 + 0];
        int Wq = map_hw[lid * 2 + 1];
        float x = px + o0 / (float)Wq;
        float y = py + o1 / (float)Hq;

        float lvl_f = (float)lid + tanhf(o2);
        float l0f = floorf(lvl_f);
        int   l0  = (int)l0f;
        float wz  = lvl_f - l0f;

        #pragma unroll
        for (int sl = 0; sl < 2; ++sl) {
            int   lv = l0 + sl;
            float wl = sl ? wz : (1.0f - wz);
            float w4[4];
            int   i4[4];
            if (lv >= 0 && lv < 4) {
                int Hs  = map_hw[lv * 2 + 0];
                int Ws  = map_hw[lv * 2 + 1];
                int off = map_offs[lv];
                float xf = x * (float)Ws - 0.5f;
                float yf = y * (float)Hs - 0.5f;
                float x0f = floorf(xf), y0f = floorf(yf);
                int   x0  = (int)x0f,  y0  = (int)y0f;
                float dx = xf - x0f, dy = yf - y0f;
                #pragma unroll
                for (int j = 0; j < 4; ++j) {
                    int xi = x0 + (j & 1);
                    int yi = y0 + (j >> 1);
                    float w = ((j & 1) ? dx : 1.0f - dx) *
                              ((j >> 1) ? dy : 1.0f - dy);
                    bool ok = (xi >= 0) && (xi < Ws) && (yi >= 0) && (yi < Hs);
                    w4[j] = ok ? (w * wl * attnw) : 0.0f;
                    i4[j] = ok ? ((off + yi * Ws + xi) << 8) : 0;  // elements
                }
            } else {
                #pragma unroll
                for (int j = 0; j < 4; ++j) { w4[j] = 0.0f; i4[j] = 0; }
            }
            #pragma unroll
            for (int j = 0; j < 4; ++j) {
                s_w[qh][t][sl * 4 + j] = w4[j];
                s_i[qh][t][sl * 4 + j] = i4[j];
            }
        }
    }
    __syncthreads();

    const int p  = t >> 5;          // 0..3
    const int s  = t & 31;          // h*4 + d8
    const int h  = s >> 2;          // 0..7
    const int d8 = s & 3;           // 0..3
    const int hp = h * 4 + p;

    float w[8];
    int   ix[8];
    #pragma unroll
    for (int j = 0; j < 8; ++j) { w[j] = s_w[qh][hp][j]; ix[j] = s_i[qh][hp][j]; }

    const unsigned short* vb = val + (size_t)b * Ns * 256 + h * 32 + d8 * 8;
    float acc[8] = {0.f, 0.f, 0.f, 0.f, 0.f, 0.f, 0.f, 0.f};
    #pragma unroll
    for (int j = 0; j < 8; ++j) {
        ushort8 v = *(const ushort8*)(vb + (size_t)ix[j]);
        #pragma unroll
        for (int c = 0; c < 8; ++c)
            acc[c] += w[j] * bf2f(v[c]);
    }
    #pragma unroll
    for (int c = 0; c < 8; ++c)
        s_red[qh][p][s][c] = acc[c];
    __syncthreads();

    if (t < 32) {
        ushort8 o;
        #pragma unroll
        for (int c = 0; c < 8; ++c) {
            float v = s_red[qh][0][t][c] + s_red[qh][1][t][c] +
                      s_red[qh][2][t][c] + s_red[qh][3][t][c];
            o[c] = f2bf(v);
        }
        *(ushort8*)(out + (size_t)bq * 256 + t * 8) = o;
    }
}

extern "C" void kernel_launch(void* const* d_in, const int* in_sizes, int n_in,
                              void* d_out, int out_size, void* d_ws, size_t ws_size,
                              hipStream_t stream) {
    const float* in_feats      = (const float*)d_in[0];
    const float* sample_priors = (const float*)d_in[1];
    const float* sample_feats  = (const float*)d_in[2];
    const int*   map_hw        = (const int*)d_in[3];
    const int*   map_offs      = (const int*)d_in[4];
    const int*   map_ids       = (const int*)d_in[5];
    const float* Wo            = (const float*)d_in[6];
    const float* bo            = (const float*)d_in[7];
    const float* Wa            = (const float*)d_in[8];
    const float* ba            = (const float*)d_in[9];
    const float* Wv            = (const float*)d_in[10];
    const float* bv            = (const float*)d_in[11];
    const float* Wout          = (const float*)d_in[12];
    const float* bout          = (const float*)d_in[13];
    float* out = (float*)d_out;

    const int B = 2, Nq = 21760, Din = 256;
    const int Ns = in_sizes[2] / (B * Din);   // 21760
    const int BQ = B * Nq;                    // 43520

    // Workspace layout
    unsigned short* val = (unsigned short*)d_out;   // [B*Ns,256] bf16 (dead before K4)
    float* C1 = (float*)d_ws;                       // [BQ,128] f32
    unsigned short* af = (unsigned short*)((char*)d_ws + (size_t)BQ * 128 * 4); // [BQ,256] bf16
    char* wbase = (char*)d_ws + (size_t)BQ * 128 * 4 + (size_t)BQ * 256 * 2;
    unsigned short* Wv_b   = (unsigned short*)wbase;          // 65536
    unsigned short* Woa_b  = Wv_b + 65536;                    // 32768 ([Wo;Wa])
    unsigned short* Wout_b = Woa_b + 32768;                   // 65536
    float* boa = (float*)(Wout_b + 65536);                    // 128 ([bo;ba])

    // K0: weight conversion (tiny)
    convert_weights<<<dim3(160), dim3(256), 0, stream>>>(
        Wv, Wo, Wa, Wout, bo, ba, Wv_b, Woa_b, Wout_b, boa);

    // K1: val = bf16(sample_feats @ Wv^T + bv)   [43520,256]x[256,256]
    gemm_mfma<4, false, true><<<dim3(BQ / 64, 1), dim3(256), 0, stream>>>(
        sample_feats, Wv_b, bv, val, B * Ns, 256, Din);

    // K2: C1 = in_feats @ [Wo;Wa]^T + [bo;ba]   [43520,256]x[256,128]
    gemm_mfma<2, false, false><<<dim3(BQ / 64, 1), dim3(128), 0, stream>>>(
        in_feats, Woa_b, boa, C1, BQ, 128, Din);

    // K3: fused softmax + trilinear sampling -> attn_feats (bf16)
    msda_sample_kernel<<<dim3(BQ / 2), dim3(256), 0, stream>>>(
        C1, sample_priors, val, map_hw, map_offs, map_ids, af, Nq, Ns);

    // K4: out = attn_feats @ Wout^T + bout   [43520,256]x[256,256]
    gemm_mfma<4, true, false><<<dim3(BQ / 64, 1), dim3(256), 0, stream>>>(
        af, Wout_b, bout, out, BQ, 256, Din);
}

// Round 5
// 128.335 us; speedup vs baseline: 4.1282x; 1.0728x over previous
//
#include <hip/hip_runtime.h>
#include <hip/hip_bf16.h>
#include <math.h>

typedef __bf16 bf16x8 __attribute__((ext_vector_type(8)));
typedef float f32x4 __attribute__((ext_vector_type(4)));
typedef unsigned short ushort8 __attribute__((ext_vector_type(8)));

static __device__ __forceinline__ unsigned short f2bf(float f) {
    union { float f; unsigned u; } c; c.f = f;
    unsigned r = c.u + 0x7FFFu + ((c.u >> 16) & 1u);   // RNE
    return (unsigned short)(r >> 16);
}
static __device__ __forceinline__ float bf2f(unsigned short u) {
    union { unsigned u; float f; } c; c.u = ((unsigned)u) << 16;
    return c.f;
}

// ---------------------------------------------------------------------------
// Weight pre-conversion: fp32 -> bf16, concatenating [Wo;Wa] and [bo;ba].
__global__ __launch_bounds__(256) void convert_weights(
    const float* __restrict__ Wv, const float* __restrict__ Wo,
    const float* __restrict__ Wa, const float* __restrict__ Wout,
    const float* __restrict__ bo, const float* __restrict__ ba,
    unsigned short* __restrict__ Wv_b, unsigned short* __restrict__ Woa_b,
    unsigned short* __restrict__ Wout_b, float* __restrict__ boa)
{
    int gid = blockIdx.x * blockDim.x + threadIdx.x;
    int stride = gridDim.x * blockDim.x;
    for (int i = gid; i < 163840; i += stride) {
        if (i < 65536)       Wv_b[i] = f2bf(Wv[i]);
        else if (i < 90112)  Woa_b[i - 65536] = f2bf(Wo[i - 65536]);
        else if (i < 98304)  Woa_b[i - 65536] = f2bf(Wa[i - 90112]);
        else                 Wout_b[i - 98304] = f2bf(Wout[i - 98304]);
    }
    if (gid < 96)       boa[gid] = bo[gid];
    else if (gid < 128) boa[gid] = ba[gid - 96];
}

// ---------------------------------------------------------------------------
// C[M,N] = A[M,K] @ W^T + bias  via mfma_f32_16x16x32_bf16.
// W is bf16 [N][K] row-major. A is fp32 (converted in staging) or bf16.
// BM=64 fixed; BN = WN*64; block = WN waves, each wave computes 64x64.
// OUT_MODE: 0 = fp32 row-major [M,N]; 1 = bf16 row-major [M,N];
//           2 = bf16 head-major val layout [B=2, H=8, NsPB, 32] (requires
//               bn==0, N==256, NsPB % BM == 0).
template<int WN, bool A_BF16, int OUT_MODE>
__global__ __launch_bounds__(WN * 64) void gemm_mfma(
    const void* __restrict__ Av, const unsigned short* __restrict__ W,
    const float* __restrict__ bias, void* __restrict__ Cv,
    int M, int N, int K, int NsPB)
{
    constexpr int BM = 64;
    constexpr int BN = WN * 64;
    constexpr int BK = 64;
    constexpr int NTHR = WN * 64;
    constexpr int LDP = 72;                 // padded row stride (shorts)

    __shared__ __align__(16) unsigned short smem[(BM + BN) * LDP];
    unsigned short* As = smem;              // [BM][LDP]
    unsigned short* Bs = smem + BM * LDP;   // [BN][LDP]

    const int bm  = blockIdx.x * BM;
    const int bn  = blockIdx.y * BN;
    const int tid = threadIdx.x;
    const int wid = tid >> 6;
    const int lane = tid & 63;
    const int lr = lane & 15;               // col-in-fragment
    const int lg = lane >> 4;               // 0..3

    f32x4 acc[4][4];
    #pragma unroll
    for (int mi = 0; mi < 4; ++mi)
        #pragma unroll
        for (int ni = 0; ni < 4; ++ni)
            acc[mi][ni] = (f32x4){0.f, 0.f, 0.f, 0.f};

    for (int kt = 0; kt < K; kt += BK) {
        // ---- stage A tile (BM x 64k) -> bf16 LDS
        if (A_BF16) {
            const unsigned short* A = (const unsigned short*)Av;
            #pragma unroll
            for (int u = tid; u < BM * 8; u += NTHR) {
                int r = u >> 3, kb = u & 7;
                ushort8 v = *(const ushort8*)(A + (size_t)(bm + r) * K + kt + kb * 8);
                *(ushort8*)(As + r * LDP + kb * 8) = v;
            }
        } else {
            const float* A = (const float*)Av;
            #pragma unroll
            for (int u = tid; u < BM * 8; u += NTHR) {
                int r = u >> 3, kb = u & 7;
                const float* src = A + (size_t)(bm + r) * K + kt + kb * 8;
                float4 f0 = *(const float4*)(src);
                float4 f1 = *(const float4*)(src + 4);
                ushort8 v;
                v[0] = f2bf(f0.x); v[1] = f2bf(f0.y);
                v[2] = f2bf(f0.z); v[3] = f2bf(f0.w);
                v[4] = f2bf(f1.x); v[5] = f2bf(f1.y);
                v[6] = f2bf(f1.z); v[7] = f2bf(f1.w);
                *(ushort8*)(As + r * LDP + kb * 8) = v;
            }
        }
        // ---- stage B tile (BN x 64k), already bf16
        #pragma unroll
        for (int u = tid; u < BN * 8; u += NTHR) {
            int r = u >> 3, kb = u & 7;
            ushort8 v = *(const ushort8*)(W + (size_t)(bn + r) * K + kt + kb * 8);
            *(ushort8*)(Bs + r * LDP + kb * 8) = v;
        }
        __syncthreads();

        #pragma unroll
        for (int kk = 0; kk < 2; ++kk) {
            bf16x8 fa[4], fb[4];
            #pragma unroll
            for (int mi = 0; mi < 4; ++mi)
                fa[mi] = *(const bf16x8*)(As + (mi * 16 + lr) * LDP + kk * 32 + lg * 8);
            #pragma unroll
            for (int ni = 0; ni < 4; ++ni)
                fb[ni] = *(const bf16x8*)(Bs + (wid * 64 + ni * 16 + lr) * LDP + kk * 32 + lg * 8);
            #pragma unroll
            for (int mi = 0; mi < 4; ++mi)
                #pragma unroll
                for (int ni = 0; ni < 4; ++ni)
                    acc[mi][ni] = __builtin_amdgcn_mfma_f32_16x16x32_bf16(
                        fa[mi], fb[ni], acc[mi][ni], 0, 0, 0);
        }
        __syncthreads();
    }

    // epilogue: C/D layout col = lane&15, row = (lane>>4)*4 + reg  [m89]
    if (OUT_MODE == 2) {
        const int b = bm / NsPB;            // block never straddles batch
        const int ns_base = bm - b * NsPB;
        #pragma unroll
        for (int ni = 0; ni < 4; ++ni) {
            int col = wid * 64 + ni * 16 + lr;        // bn == 0
            int h   = col >> 5;
            int ch  = col & 31;
            float bv = bias[col];
            unsigned short* dst = (unsigned short*)Cv +
                (size_t)(b * 8 + h) * NsPB * 32 + ch;
            #pragma unroll
            for (int mi = 0; mi < 4; ++mi) {
                #pragma unroll
                for (int r = 0; r < 4; ++r) {
                    int ns = ns_base + mi * 16 + lg * 4 + r;
                    dst[(size_t)ns * 32] = f2bf(acc[mi][ni][r] + bv);
                }
            }
        }
    } else {
        #pragma unroll
        for (int ni = 0; ni < 4; ++ni) {
            int col = bn + wid * 64 + ni * 16 + lr;
            float bv = bias[col];
            #pragma unroll
            for (int mi = 0; mi < 4; ++mi) {
                #pragma unroll
                for (int r = 0; r < 4; ++r) {
                    int row = bm + mi * 16 + lg * 4 + r;
                    if (OUT_MODE == 1) {
                        ((unsigned short*)Cv)[(size_t)row * N + col] =
                            f2bf(acc[mi][ni][r] + bv);
                    } else {
                        ((float*)Cv)[(size_t)row * N + col] = acc[mi][ni][r] + bv;
                    }
                }
            }
        }
    }
}

// ---------------------------------------------------------------------------
// Per-query fused: softmax over P, sample-position math, trilinear gather of
// bf16 val in head-major layout [B,H,Ns,32], weighted sum -> attn_feats
// (bf16). 2 queries per block (128 threads each). Thread (p,h,d8) does 8
// unconditional 16B loads + fp32 FMA; p reduced via shfl_xor(32) + one
// small LDS exchange. Grid XCD-chunk swizzled.
__global__ __launch_bounds__(256) void msda_sample_kernel(
    const float* __restrict__ C1,        // [BQ,128]: 96 offs + 32 attn logits
    const float* __restrict__ priors,    // [BQ,2]
    const unsigned short* __restrict__ val, // [B,8,Ns,32] bf16
    const int*   __restrict__ map_hw,    // [4][2] (H,W)
    const int*   __restrict__ map_offs,  // [4]
    const int*   __restrict__ map_ids,   // [B,Ns]
    unsigned short* __restrict__ out,    // [BQ,256] bf16
    int Nq, int Ns)
{
    // XCD-chunked swizzle (nwg % 8 == 0): contiguous chunk per XCD
    const int swz = (blockIdx.x & 7) * (gridDim.x >> 3) + (blockIdx.x >> 3);
    const int qh  = threadIdx.x >> 7;        // which query of the pair
    const int bq  = swz * 2 + qh;
    const int t   = threadIdx.x & 127;
    const int b   = bq / Nq;
    const int q   = bq - b * Nq;

    __shared__ float s_w[2][32][9];
    __shared__ int   s_i[2][32][9];
    __shared__ float s_red[2][32][9];

    if (t < 32) {
        const int h = t >> 2;
        const int p = t & 3;
        const float* sc = C1 + (size_t)bq * 128;
        float o0 = sc[h * 12 + p * 3 + 0];
        float o1 = sc[h * 12 + p * 3 + 1];
        float o2 = sc[h * 12 + p * 3 + 2];
        float logit = sc[96 + h * 4 + p];

        // softmax over the 4 points of this head (lanes 4h..4h+3 in-wave)
        float m = logit;
        m = fmaxf(m, __shfl_xor(m, 1));
        m = fmaxf(m, __shfl_xor(m, 2));
        float e = expf(logit - m);
        float s = e;
        s += __shfl_xor(s, 1);
        s += __shfl_xor(s, 2);
        float attnw = e / s;

        int lid = map_ids[(size_t)b * Ns + q];
        float px = priors[(size_t)bq * 2 + 0];
        float py = priors[(size_t)bq * 2 + 1];
        int Hq = map_hw[lid * 2 + 0];
        int Wq = map_hw[lid * 2 + 1];
        float x = px + o0 / (float)Wq;
        float y = py + o1 / (float)Hq;

        float lvl_f = (float)lid + tanhf(o2);
        float l0f = floorf(lvl_f);
        int   l0  = (int)l0f;
        float wz  = lvl_f - l0f;

        #pragma unroll
        for (int sl = 0; sl < 2; ++sl) {
            int   lv = l0 + sl;
            float wl = sl ? wz : (1.0f - wz);
            float w4[4];
            int   i4[4];
            if (lv >= 0 && lv < 4) {
                int Hs  = map_hw[lv * 2 + 0];
                int Ws  = map_hw[lv * 2 + 1];
                int off = map_offs[lv];
                float xf = x * (float)Ws - 0.5f;
                float yf = y * (float)Hs - 0.5f;
                float x0f = floorf(xf), y0f = floorf(yf);
                int   x0  = (int)x0f,  y0  = (int)y0f;
                float dx = xf - x0f, dy = yf - y0f;
                #pragma unroll
                for (int j = 0; j < 4; ++j) {
                    int xi = x0 + (j & 1);
                    int yi = y0 + (j >> 1);
                    float w = ((j & 1) ? dx : 1.0f - dx) *
                              ((j >> 1) ? dy : 1.0f - dy);
                    bool ok = (xi >= 0) && (xi < Ws) && (yi >= 0) && (yi < Hs);
                    w4[j] = ok ? (w * wl * attnw) : 0.0f;
                    i4[j] = ok ? ((off + yi * Ws + xi) << 5) : 0;  // row elems
                }
            } else {
                #pragma unroll
                for (int j = 0; j < 4; ++j) { w4[j] = 0.0f; i4[j] = 0; }
            }
            #pragma unroll
            for (int j = 0; j < 4; ++j) {
                s_w[qh][t][sl * 4 + j] = w4[j];
                s_i[qh][t][sl * 4 + j] = i4[j];
            }
        }
    }
    __syncthreads();

    const int p  = t >> 5;          // 0..3
    const int s  = t & 31;          // h*4 + d8
    const int h  = s >> 2;          // 0..7
    const int d8 = s & 3;           // 0..3
    const int hp = h * 4 + p;

    float w[8];
    int   ix[8];
    #pragma unroll
    for (int j = 0; j < 8; ++j) { w[j] = s_w[qh][hp][j]; ix[j] = s_i[qh][hp][j]; }

    const unsigned short* vb = val + (size_t)(b * 8 + h) * Ns * 32 + d8 * 8;
    float acc[8] = {0.f, 0.f, 0.f, 0.f, 0.f, 0.f, 0.f, 0.f};
    #pragma unroll
    for (int j = 0; j < 8; ++j) {
        ushort8 v = *(const ushort8*)(vb + (size_t)ix[j]);
        #pragma unroll
        for (int c = 0; c < 8; ++c)
            acc[c] += w[j] * bf2f(v[c]);
    }

    // reduce p-pairs within each wave: lanes (t, t^32) hold p0/p1 (wave A)
    // and p2/p3 (wave B) for the same s
    #pragma unroll
    for (int c = 0; c < 8; ++c)
        acc[c] += __shfl_xor(acc[c], 32);

    if (t >= 64 && t < 96) {        // wave B, lanes 0..31: p2+p3 partials
        #pragma unroll
        for (int c = 0; c < 8; ++c)
            s_red[qh][t - 64][c] = acc[c];
    }
    __syncthreads();

    if (t < 32) {                   // wave A, lanes 0..31: p0+p1 partials
        ushort8 o;
        #pragma unroll
        for (int c = 0; c < 8; ++c)
            o[c] = f2bf(acc[c] + s_red[qh][t][c]);
        *(ushort8*)(out + (size_t)bq * 256 + t * 8) = o;
    }
}

extern "C" void kernel_launch(void* const* d_in, const int* in_sizes, int n_in,
                              void* d_out, int out_size, void* d_ws, size_t ws_size,
                              hipStream_t stream) {
    const float* in_feats      = (const float*)d_in[0];
    const float* sample_priors = (const float*)d_in[1];
    const float* sample_feats  = (const float*)d_in[2];
    const int*   map_hw        = (const int*)d_in[3];
    const int*   map_offs      = (const int*)d_in[4];
    const int*   map_ids       = (const int*)d_in[5];
    const float* Wo            = (const float*)d_in[6];
    const float* bo            = (const float*)d_in[7];
    const float* Wa            = (const float*)d_in[8];
    const float* ba            = (const float*)d_in[9];
    const float* Wv            = (const float*)d_in[10];
    const float* bv            = (const float*)d_in[11];
    const float* Wout          = (const float*)d_in[12];
    const float* bout          = (const float*)d_in[13];
    float* out = (float*)d_out;

    const int B = 2, Nq = 21760, Din = 256;
    const int Ns = in_sizes[2] / (B * Din);   // 21760
    const int BQ = B * Nq;                    // 43520

    // Workspace layout
    unsigned short* val = (unsigned short*)d_out;   // [B,8,Ns,32] bf16 (dead before K4)
    float* C1 = (float*)d_ws;                       // [BQ,128] f32
    unsigned short* af = (unsigned short*)((char*)d_ws + (size_t)BQ * 128 * 4); // [BQ,256] bf16
    char* wbase = (char*)d_ws + (size_t)BQ * 128 * 4 + (size_t)BQ * 256 * 2;
    unsigned short* Wv_b   = (unsigned short*)wbase;          // 65536
    unsigned short* Woa_b  = Wv_b + 65536;                    // 32768 ([Wo;Wa])
    unsigned short* Wout_b = Woa_b + 32768;                   // 65536
    float* boa = (float*)(Wout_b + 65536);                    // 128 ([bo;ba])

    // K0: weight conversion (tiny)
    convert_weights<<<dim3(160), dim3(256), 0, stream>>>(
        Wv, Wo, Wa, Wout, bo, ba, Wv_b, Woa_b, Wout_b, boa);

    // K1: val = bf16(sample_feats @ Wv^T + bv), head-major layout
    gemm_mfma<4, false, 2><<<dim3(BQ / 64, 1), dim3(256), 0, stream>>>(
        sample_feats, Wv_b, bv, val, B * Ns, 256, Din, Ns);

    // K2: C1 = in_feats @ [Wo;Wa]^T + [bo;ba]   [43520,256]x[256,128]
    gemm_mfma<2, false, 0><<<dim3(BQ / 64, 1), dim3(128), 0, stream>>>(
        in_feats, Woa_b, boa, C1, BQ, 128, Din, Ns);

    // K3: fused softmax + trilinear sampling -> attn_feats (bf16)
    msda_sample_kernel<<<dim3(BQ / 2), dim3(256), 0, stream>>>(
        C1, sample_priors, val, map_hw, map_offs, map_ids, af, Nq, Ns);

    // K4: out = attn_feats @ Wout^T + bout   [43520,256]x[256,256]
    gemm_mfma<4, true, 0><<<dim3(BQ / 64, 1), dim3(256), 0, stream>>>(
        af, Wout_b, bout, out, BQ, 256, Din, Ns);
}